// Round 9
// baseline (160.767 us; speedup 1.0000x reference)
//
#include <hip/hip_runtime.h>
#include <math.h>

#define NB 16
#define NS 48
#define NL 64
#define NQ 32
#define NE 300
#define NF 256
#define KP 320            // padded K for embeddings (bf16)
#define QROWS 36          // qe rows per b (32 + zero pad for taps)

typedef __attribute__((ext_vector_type(8))) short short8;
typedef __attribute__((ext_vector_type(4))) float f32x4;

#define MFMA(a,b,c) __builtin_amdgcn_mfma_f32_16x16x32_bf16((a),(b),(c),0,0,0)

__device__ __forceinline__ unsigned short f2bf(float f) {
    unsigned u = __float_as_uint(f);
    u += 0x7fff + ((u >> 16) & 1);           // RNE
    return (unsigned short)(u >> 16);
}

__device__ __forceinline__ float wave_reduce_sum(float v) {
#pragma unroll
    for (int off = 32; off; off >>= 1) v += __shfl_xor(v, off, 64);
    return v;
}

// four independent top-5 pools, interleaved for ILP
__device__ __forceinline__ void top5_pool4(float v0, float v1, float v2, float v3,
                                           int lane, float* mx, float* mn) {
    float s0 = 0.f, s1 = 0.f, s2 = 0.f, s3 = 0.f;
    float x0 = 0.f, x1 = 0.f, x2 = 0.f, x3 = 0.f;
#pragma unroll
    for (int i = 0; i < 5; ++i) {
        float m0 = v0, m1 = v1, m2 = v2, m3 = v3;
#pragma unroll
        for (int off = 32; off; off >>= 1) {
            m0 = fmaxf(m0, __shfl_xor(m0, off, 64));
            m1 = fmaxf(m1, __shfl_xor(m1, off, 64));
            m2 = fmaxf(m2, __shfl_xor(m2, off, 64));
            m3 = fmaxf(m3, __shfl_xor(m3, off, 64));
        }
        if (i == 0) { x0 = m0; x1 = m1; x2 = m2; x3 = m3; }
        s0 += m0; s1 += m1; s2 += m2; s3 += m3;
        unsigned long long k0 = __ballot(v0 == m0);
        unsigned long long k1 = __ballot(v1 == m1);
        unsigned long long k2 = __ballot(v2 == m2);
        unsigned long long k3 = __ballot(v3 == m3);
        if (lane == __ffsll(k0) - 1) v0 = -3.4e38f;
        if (lane == __ffsll(k1) - 1) v1 = -3.4e38f;
        if (lane == __ffsll(k2) - 1) v2 = -3.4e38f;
        if (lane == __ffsll(k3) - 1) v3 = -3.4e38f;
    }
    mx[0] = x0; mx[1] = x1; mx[2] = x2; mx[3] = x3;
    mn[0] = s0 * 0.2f; mn[1] = s1 * 0.2f; mn[2] = s2 * 0.2f; mn[3] = s3 * 0.2f;
}

// ---------- pack conv_w into MFMA B-fragment order (certified r6); zero qcssq + ctr
__global__ void wb2_kernel(const float* __restrict__ conv_w, short8* __restrict__ Wb2,
                           unsigned int* __restrict__ done_ctr,
                           float* __restrict__ qcssq) {
    if (blockIdx.x == 0 && threadIdx.x == 0) done_ctr[0] = 0u;
    int i = blockIdx.x * 256 + threadIdx.x;      // 120*256 = 30720
    if (i < NB * NQ) qcssq[i] = 0.f;
    if (i >= 120 * 256) return;
    int rl = i & 15;
    int ftile = (i >> 4) & 15;
    int c = i >> 8;
    int kg = c & 3, rest = c >> 2;
    int ks = rest % 10, j = rest / 10;
    int f = ftile * 16 + rl;
    int k0 = ks * 32 + kg * 8;
    const float* src = conv_w + (size_t)(f * 3 + j) * NE;
    short8 h;
#pragma unroll
    for (int e = 0; e < 8; ++e) {
        int k = k0 + e;
        h[e] = (short)((k < NE) ? f2bf(src[k]) : (unsigned short)0);
    }
    Wb2[i] = h;
}

// ---------- q_emb gather -> taps layout + A-fragments + fp32 q_norm (certified r6)
__global__ void qe_kernel(const int* __restrict__ question, const float* __restrict__ embeds,
                          unsigned short* __restrict__ qe, short8* __restrict__ qef,
                          float* __restrict__ q_norm) {
    int row = blockIdx.x;                        // b*36 + r
    int b = row / QROWS, r = row % QROWS;
    int l = threadIdx.x;
    unsigned short* dst = qe + (size_t)row * KP;
    if (r < NQ) {
        int tok = question[b * NQ + r];
        const float4* rp = (const float4*)(embeds + (size_t)tok * NE);
        short8 h = {0, 0, 0, 0, 0, 0, 0, 0};
        float ss = 0.f;
        if (l < 38) {
            float4 v0 = rp[2 * l];
            ss += v0.x * v0.x + v0.y * v0.y + v0.z * v0.z + v0.w * v0.w;
            h[0] = (short)f2bf(v0.x); h[1] = (short)f2bf(v0.y);
            h[2] = (short)f2bf(v0.z); h[3] = (short)f2bf(v0.w);
            if (2 * l + 1 < 75) {
                float4 v1 = rp[2 * l + 1];
                ss += v1.x * v1.x + v1.y * v1.y + v1.z * v1.z + v1.w * v1.w;
                h[4] = (short)f2bf(v1.x); h[5] = (short)f2bf(v1.y);
                h[6] = (short)f2bf(v1.z); h[7] = (short)f2bf(v1.w);
            }
        }
        if (l < 40) {
            *(short8*)(dst + 8 * l) = h;
            qef[((size_t)(b * 2 + (r >> 4)) * 40 + l) * 16 + (r & 15)] = h;
        }
        ss = wave_reduce_sum(ss);
        if (l == 0) q_norm[b * NQ + r] = sqrtf(ss);
    } else {
        if (l < 40) {
            short8 z = {0, 0, 0, 0, 0, 0, 0, 0};
            *(short8*)(dst + 8 * l) = z;
        }
    }
}

// ---------- q_conv via MFMA -> A-fragments + partial qc ssq (folded qcn)
__global__ __launch_bounds__(256) void qconv_mfma_kernel(
        const unsigned short* __restrict__ qe, const short8* __restrict__ Wb2,
        short8* __restrict__ qcf, float* __restrict__ qcssq) {
    __shared__ unsigned short tile[NQ][72];
    int b = blockIdx.x >> 2, fq = blockIdx.x & 3;
    int tid = threadIdx.x, lane = tid & 63, w = tid >> 6;
    int rl = lane & 15, kg = lane >> 4;
    int ftile = fq * 4 + w;
    f32x4 acc0 = (f32x4){0.f, 0.f, 0.f, 0.f};
    f32x4 acc1 = (f32x4){0.f, 0.f, 0.f, 0.f};
    for (int j = 0; j < 3; ++j) {
#pragma unroll 2
        for (int ks = 0; ks < 10; ++ks) {
            int k = ks * 32 + kg * 8;
            int c = (j * 10 + ks) * 4 + kg;
            short8 a0 = *(const short8*)(qe + ((size_t)(b * QROWS) + rl + j) * KP + k);
            short8 a1 = *(const short8*)(qe + ((size_t)(b * QROWS) + 16 + rl + j) * KP + k);
            short8 bb = Wb2[(c * 16 + ftile) * 16 + rl];
            acc0 = MFMA(a0, bb, acc0);
            acc1 = MFMA(a1, bb, acc1);
        }
    }
    int fl = w * 16 + rl;
#pragma unroll
    for (int reg = 0; reg < 4; ++reg) {
        tile[kg * 4 + reg][fl] = f2bf(acc0[reg]);
        tile[16 + kg * 4 + reg][fl] = f2bf(acc1[reg]);
    }
    __syncthreads();
    // emit fragments
    {
        int mh = tid >> 7, c_local = (tid >> 4) & 7, rl2 = tid & 15;
        short8 h = *(const short8*)(&tile[mh * 16 + rl2][c_local * 8]);
        qcf[((size_t)(b * 2 + mh) * 32 + 8 * fq + c_local) * 16 + rl2] = h;
    }
    // partial sum-of-squares over this block's 64 f for each q
    {
        int qq = tid >> 3, fgrp = tid & 7;
        short8 h = *(const short8*)(&tile[qq][fgrp * 8]);
        float ss = 0.f;
#pragma unroll
        for (int e = 0; e < 8; ++e) {
            float v = __uint_as_float(((unsigned)(unsigned short)h[e]) << 16);
            ss += v * v;
        }
        ss += __shfl_xor(ss, 1, 64);
        ss += __shfl_xor(ss, 2, 64);
        ss += __shfl_xor(ss, 4, 64);
        if (fgrp == 0) atomicAdd(&qcssq[b * NQ + qq], ss);
    }
}

// ---------- K_pack: s_emb gather -> global fragments sB[bs][c40][t64] + fp32 snorm
__global__ __launch_bounds__(256) void pack_kernel(
        const int* __restrict__ sentences, const float* __restrict__ embeds,
        short8* __restrict__ sB, float* __restrict__ snorm_g) {
    __shared__ unsigned short stg[16][328];    // 10.5 KB
    __shared__ int toks[NL];
    int bs = blockIdx.x;
    int tid = threadIdx.x, lane = tid & 63, w = tid >> 6;
    if (tid < NL) toks[tid] = sentences[(size_t)bs * NL + tid];
    __syncthreads();
    short8* sbb = sB + (size_t)bs * 40 * 64;
    for (int it = 0; it < 4; ++it) {
#pragma unroll
        for (int i = 0; i < 4; ++i) {
            int r16 = w * 4 + i;
            int r = it * 16 + r16;
            const float4* rp = (const float4*)(embeds + (size_t)toks[r] * NE);
            float ss;
            {
                float4 v = rp[lane];
                ss = v.x * v.x + v.y * v.y + v.z * v.z + v.w * v.w;
                ushort4 h = {f2bf(v.x), f2bf(v.y), f2bf(v.z), f2bf(v.w)};
                *(ushort4*)&stg[r16][4 * lane] = h;
            }
            if (lane < 11) {
                float4 v = rp[64 + lane];
                ss += v.x * v.x + v.y * v.y + v.z * v.z + v.w * v.w;
                ushort4 h = {f2bf(v.x), f2bf(v.y), f2bf(v.z), f2bf(v.w)};
                *(ushort4*)&stg[r16][256 + 4 * lane] = h;
            } else if (lane < 16) {
                ushort4 z = {0, 0, 0, 0};
                *(ushort4*)&stg[r16][256 + 4 * lane] = z;
            }
            ss = wave_reduce_sum(ss);
            if (lane == 0) snorm_g[bs * NL + r] = sqrtf(ss);
        }
        __syncthreads();
        {
            int c = tid >> 4, rl = tid & 15;
            for (; c < 40; c += 16) {
                short8 h = *(const short8*)&stg[rl][c * 8];
                sbb[(size_t)c * 64 + it * 16 + rl] = h;
            }
        }
        __syncthreads();
    }
}

// ---------- K_ins: sim_ins MFMA + pool -> fpool_ins. High occupancy (8.6 KB LDS).
__global__ __launch_bounds__(256) void ins_kernel(
        const int* __restrict__ sentences, const int* __restrict__ question,
        const short8* __restrict__ sB, const short8* __restrict__ qef,
        const float* __restrict__ snorm_g, const float* __restrict__ q_norm,
        float2* __restrict__ fpool_ins) {
    __shared__ float sim[NQ][66];              // 8448 B
    __shared__ float qn_s[NQ], qmf_s[NQ];
    int bs = blockIdx.x, b = bs / NS;
    int tid = threadIdx.x, lane = tid & 63, w = tid >> 6;
    int rl = lane & 15, kg = lane >> 4;
    int t = (w << 4) + rl;
    if (tid < NQ) qn_s[tid] = q_norm[b * NQ + tid];
    else if (tid < 2 * NQ) {
        int q = tid - NQ;
        qmf_s[q] = (question[b * NQ + q] > 1) ? 1.f : 0.f;
    }
    float sn_t = snorm_g[bs * NL + t];
    float sm_t = (sentences[(size_t)bs * NL + t] > 1) ? 1.f : 0.f;
    __syncthreads();
    f32x4 i0 = (f32x4){0.f, 0.f, 0.f, 0.f};
    f32x4 i1 = (f32x4){0.f, 0.f, 0.f, 0.f};
    const short8* qf = qef + (size_t)(b * 80) * 16;
    const short8* sbb = sB + (size_t)bs * 40 * 64;
#pragma unroll 2
    for (int ks = 0; ks < 10; ++ks) {
        int c = ks * 4 + kg;
        short8 bB = sbb[(size_t)c * 64 + t];
        i0 = MFMA(qf[c * 16 + rl], bB, i0);
        i1 = MFMA(qf[(40 + c) * 16 + rl], bB, i1);
    }
    float inv_t = sm_t / sn_t;
#pragma unroll
    for (int reg = 0; reg < 4; ++reg) {
        int q0 = kg * 4 + reg;
        sim[q0][t] = i0[reg] / qn_s[q0] * inv_t * qmf_s[q0];
        int q1 = 16 + kg * 4 + reg;
        sim[q1][t] = i1[reg] / qn_s[q1] * inv_t * qmf_s[q1];
    }
    __syncthreads();
    int q0 = w << 3;
    float mx[4], mn[4];
    top5_pool4(sim[q0 + 0][lane], sim[q0 + 1][lane], sim[q0 + 2][lane], sim[q0 + 3][lane],
               lane, mx, mn);
    if (lane == 0)
#pragma unroll
        for (int p = 0; p < 4; ++p)
            fpool_ins[(size_t)bs * NQ + q0 + p] = (float2){mx[p], mn[p]};
    top5_pool4(sim[q0 + 4][lane], sim[q0 + 5][lane], sim[q0 + 6][lane], sim[q0 + 7][lane],
               lane, mx, mn);
    if (lane == 0)
#pragma unroll
        for (int p = 0; p < 4; ++p)
            fpool_ins[(size_t)bs * NQ + q0 + 4 + p] = (float2){mx[p], mn[p]};
}

// ---------- K_convsens: stage sB->LDS, conv MFMA (A from LDS) -> s_conv LDS (overlay)
//            -> sens + pools + head + fused loss
#define ST_T 66                                // t-slots incl 2 zero tail rows
#define SC_PITCH 512                           // 256 bf16 per row
#define SIM_OFF (64 * SC_PITCH)                // 32768
#define SIM_PITCH 66
#define DYN_LDS (40 * ST_T * 16)               // 42240 (> 32768+8448=41216 overlay)
extern __shared__ char ldsc[];
__global__ __launch_bounds__(256) void convsens_kernel(
        const int* __restrict__ question, const float* __restrict__ sim_oh,
        const short8* __restrict__ sB, const short8* __restrict__ Wb2,
        const short8* __restrict__ qcf, const float* __restrict__ qcssq,
        const float2* __restrict__ fpool_ins,
        const float* __restrict__ lin_w, const float* __restrict__ lin_b,
        const int* __restrict__ tsent, const int* __restrict__ tdoc,
        unsigned int* __restrict__ done_ctr,
        float* __restrict__ sent_ws, float* __restrict__ d_out) {
    __shared__ float scnorm[NL];
    __shared__ float qcn_s[NQ];
    __shared__ float wq[4];
    __shared__ int lastflag;
    __shared__ float red2[4];
    __shared__ float dred[NB];

    int tid = threadIdx.x, lane = tid & 63, w = tid >> 6;
    int rl = lane & 15, kg = lane >> 4;
    int bs = blockIdx.x, b = bs / NS;
    int t = (w << 4) + rl, t7 = t & 7;

    if (tid < NQ) qcn_s[tid] = sqrtf(qcssq[b * NQ + tid]);

    // ---- Phase A0: cooperative stage sB -> LDS (+2 zero tail rows per c)
    short8* lds_s8 = (short8*)ldsc;
    const short8* sbb = sB + (size_t)bs * 40 * 64;
    {
        short8 z = {0, 0, 0, 0, 0, 0, 0, 0};
        for (int c = w; c < 40; c += 4) {
            lds_s8[c * ST_T + lane] = sbb[(size_t)c * 64 + lane];
            if (lane < 2) lds_s8[c * ST_T + 64 + lane] = z;
        }
    }
    __syncthreads();

    // ---- Phase A: conv MFMA. wave w owns f-tiles 4w..4w+3; A from LDS.
    f32x4 cacc[4][4];
#pragma unroll
    for (int m = 0; m < 4; ++m)
#pragma unroll
        for (int nn = 0; nn < 4; ++nn) cacc[m][nn] = (f32x4){0.f, 0.f, 0.f, 0.f};
    for (int j = 0; j < 3; ++j) {
#pragma unroll 2
        for (int ks = 0; ks < 10; ++ks) {
            int cA = ks * 4 + kg;
            int c = (j * 10 + ks) * 4 + kg;
            short8 a[4], bb[4];
#pragma unroll
            for (int m = 0; m < 4; ++m)
                a[m] = lds_s8[cA * ST_T + m * 16 + rl + j];
#pragma unroll
            for (int nn = 0; nn < 4; ++nn)
                bb[nn] = Wb2[(c * 16 + (w * 4 + nn)) * 16 + rl];
#pragma unroll
            for (int m = 0; m < 4; ++m)
#pragma unroll
                for (int nn = 0; nn < 4; ++nn)
                    cacc[m][nn] = MFMA(a[m], bb[nn], cacc[m][nn]);
        }
    }
    __syncthreads();   // sB-LDS dead; overlay with s_conv

    // ---- Phase B: write s_conv bf16 (swizzled) into LDS
#pragma unroll
    for (int m = 0; m < 4; ++m)
#pragma unroll
        for (int nn = 0; nn < 4; ++nn) {
            int f = (w * 4 + nn) * 16 + rl;
#pragma unroll
            for (int reg = 0; reg < 4; ++reg) {
                int tr = m * 16 + kg * 4 + reg;
                *(unsigned short*)(ldsc + tr * SC_PITCH +
                                   (((f >> 3) ^ (tr & 7)) << 4) + ((f & 7) << 1)) =
                    f2bf(cacc[m][nn][reg]);
            }
        }
    __syncthreads();

    // ---- Phase C: prefetch oh; sens MFMA (K=256) + scnorm via Gram diag
    float oh[8];
#pragma unroll
    for (int qi = 0; qi < 8; ++qi) {
        int q = (w << 3) + qi;
        oh[qi] = sim_oh[((size_t)bs * NQ + q) * NL + lane];
    }
    {
        f32x4 sacc0 = (f32x4){0.f, 0.f, 0.f, 0.f};
        f32x4 sacc1 = (f32x4){0.f, 0.f, 0.f, 0.f};
        f32x4 nB = (f32x4){0.f, 0.f, 0.f, 0.f};
        const short8* qc = qcf + (size_t)(b * 64) * 16;
#pragma unroll 2
        for (int ks = 0; ks < 8; ++ks) {
            int c = ks * 4 + kg;
            short8 bB = *(const short8*)(ldsc + t * SC_PITCH + ((c ^ t7) << 4));
            sacc0 = MFMA(qc[c * 16 + rl], bB, sacc0);
            sacc1 = MFMA(qc[(32 + c) * 16 + rl], bB, sacc1);
            nB = MFMA(bB, bB, nB);
        }
        if (kg == (rl >> 2)) scnorm[t] = sqrtf(nB[rl & 3]);
        __syncthreads();

        // ---- Phase D: scale + write sim_sens
        float inv_t = 1.f / scnorm[t];
#pragma unroll
        for (int reg = 0; reg < 4; ++reg) {
            int q0 = kg * 4 + reg;
            *(float*)(ldsc + SIM_OFF + (q0 * SIM_PITCH + t) * 4) =
                sacc0[reg] / qcn_s[q0] * inv_t;
            int q1 = 16 + kg * 4 + reg;
            *(float*)(ldsc + SIM_OFF + (q1 * SIM_PITCH + t) * 4) =
                sacc1[reg] / qcn_s[q1] * inv_t;
        }
    }
    __syncthreads();

    // ---- Phase E: pools + head
    {
        float lw0 = lin_w[0], lw1 = lin_w[1], lw2 = lin_w[2];
        float lw3 = lin_w[3], lw4 = lin_w[4], lw5 = lin_w[5];
        float lb = lin_b[0];
        int q0 = w << 3;
        float sv[8];
#pragma unroll
        for (int qi = 0; qi < 8; ++qi)
            sv[qi] = *(float*)(ldsc + SIM_OFF + ((q0 + qi) * SIM_PITCH + lane) * 4);
        float mxs[8], mns[8], mxo[8], mno[8];
        top5_pool4(sv[0], sv[1], sv[2], sv[3], lane, mxs, mns);
        top5_pool4(sv[4], sv[5], sv[6], sv[7], lane, mxs + 4, mns + 4);
        top5_pool4(oh[0], oh[1], oh[2], oh[3], lane, mxo, mno);
        top5_pool4(oh[4], oh[5], oh[6], oh[7], lane, mxo + 4, mno + 4);
        float psum = 0.f;
#pragma unroll
        for (int qi = 0; qi < 8; ++qi) {
            float2 fp = fpool_ins[(size_t)bs * NQ + q0 + qi];
            float z = fp.x * lw0 + fp.y * lw1 + mxs[qi] * lw2 + mns[qi] * lw3 +
                      mxo[qi] * lw4 + mno[qi] * lw5 + lb;
            psum += 1.f / (1.f + expf(-z));
        }
        if (lane == 0) wq[w] = psum;
    }
    __syncthreads();
    if (tid == 0) {
        float sent = (wq[0] + wq[1] + wq[2] + wq[3]) * (1.f / 32.f);
        __hip_atomic_store(&sent_ws[bs], sent, __ATOMIC_RELEASE, __HIP_MEMORY_SCOPE_AGENT);
        d_out[1 + bs] = sent;
        unsigned old = atomicAdd(done_ctr, 1u);
        lastflag = (old == (unsigned)(NB * NS - 1)) ? 1 : 0;
    }
    __syncthreads();

    if (lastflag) {
        float acc_l = 0.f;
        for (int i = tid; i < NB * NS; i += 256) {
            float p = __hip_atomic_load(&sent_ws[i], __ATOMIC_ACQUIRE, __HIP_MEMORY_SCOPE_AGENT);
            float tt2 = (float)tsent[i];
            acc_l += tt2 * logf(p) + (1.f - tt2) * logf(1.f - p);
        }
        acc_l = wave_reduce_sum(acc_l);
        if ((tid & 63) == 0) red2[tid >> 6] = acc_l;
        if (tid < NB) {
            float m = -3.4e38f;
            for (int s = 0; s < NS; ++s)
                m = fmaxf(m, __hip_atomic_load(&sent_ws[tid * NS + s], __ATOMIC_ACQUIRE,
                                               __HIP_MEMORY_SCOPE_AGENT));
            d_out[1 + NB * NS + tid] = m;
            float tt2 = (float)tdoc[tid];
            dred[tid] = tt2 * logf(m) + (1.f - tt2) * logf(1.f - m);
        }
        __syncthreads();
        if (tid == 0) {
            float sal = -(red2[0] + red2[1] + red2[2] + red2[3]) / (float)(NB * NS);
            float dsum = 0.f;
            for (int i = 0; i < NB; ++i) dsum += dred[i];
            float dal = -dsum / (float)NB;
            d_out[0] = 0.5f * (sal + dal);
        }
    }
}

extern "C" void kernel_launch(void* const* d_in, const int* in_sizes, int n_in,
                              void* d_out, int out_size, void* d_ws, size_t ws_size,
                              hipStream_t stream) {
    const int* sentences = (const int*)d_in[0];
    const int* question = (const int*)d_in[1];
    const int* tsent = (const int*)d_in[2];
    const int* tdoc = (const int*)d_in[3];
    const float* sim_oh = (const float*)d_in[4];
    const float* embeds = (const float*)d_in[5];
    const float* conv_w = (const float*)d_in[6];
    const float* lin_w = (const float*)d_in[7];
    const float* lin_b = (const float*)d_in[8];
    float* out = (float*)d_out;

    char* wsc = (char*)d_ws;
    short8* Wb2            = (short8*)(wsc);                     // 491520 B
    unsigned short* qe_old = (unsigned short*)(wsc + 491520);    // 368640 B
    short8* qef            = (short8*)(wsc + 860160);            // 327680 B
    short8* qcf            = (short8*)(wsc + 1187840);           // 262144 B
    float* q_norm          = (float*)(wsc + 1449984);            // 2048 B
    float* qcssq           = (float*)(wsc + 1452032);            // 2048 B
    float* sent_ws         = (float*)(wsc + 1454080);            // 3072 B
    unsigned int* done_ctr = (unsigned int*)(wsc + 1457152);     // 16 B
    float* snorm_g         = (float*)(wsc + 1457168);            // 196608 B
    float2* fpool_ins      = (float2*)(wsc + 1653776);           // 196608 B
    short8* sB             = (short8*)(wsc + 1850384);           // 31457280 B

    hipFuncSetAttribute(reinterpret_cast<const void*>(convsens_kernel),
                        hipFuncAttributeMaxDynamicSharedMemorySize, DYN_LDS);

    wb2_kernel<<<120, 256, 0, stream>>>(conv_w, Wb2, done_ctr, qcssq);
    qe_kernel<<<NB * QROWS, 64, 0, stream>>>(question, embeds, qe_old, qef, q_norm);
    qconv_mfma_kernel<<<NB * 4, 256, 0, stream>>>(qe_old, Wb2, qcf, qcssq);
    pack_kernel<<<NB * NS, 256, 0, stream>>>(sentences, embeds, sB, snorm_g);
    ins_kernel<<<NB * NS, 256, 0, stream>>>(sentences, question, sB, qef,
                                            snorm_g, q_norm, fpool_ins);
    convsens_kernel<<<NB * NS, 256, DYN_LDS, stream>>>(
        question, sim_oh, sB, Wb2, qcf, qcssq, fpool_ins,
        lin_w, lin_b, tsent, tdoc, done_ctr, sent_ws, out);
}

// Round 10
// 135.898 us; speedup vs baseline: 1.1830x; 1.1830x over previous
//
#include <hip/hip_runtime.h>
#include <math.h>

#define NB 16
#define NS 48
#define NL 64
#define NQ 32
#define NE 300
#define NF 256
#define KP 320
#define QROWS 36

typedef __attribute__((ext_vector_type(8))) short short8;
typedef __attribute__((ext_vector_type(4))) float f32x4;

#define MFMA(a,b,c) __builtin_amdgcn_mfma_f32_16x16x32_bf16((a),(b),(c),0,0,0)

__device__ __forceinline__ unsigned short f2bf(float f) {
    unsigned u = __float_as_uint(f);
    u += 0x7fff + ((u >> 16) & 1);           // RNE
    return (unsigned short)(u >> 16);
}

__device__ __forceinline__ float wave_reduce_sum(float v) {
#pragma unroll
    for (int off = 32; off; off >>= 1) v += __shfl_xor(v, off, 64);
    return v;
}

// four independent top-5 pools, interleaved for ILP
__device__ __forceinline__ void top5_pool4(float v0, float v1, float v2, float v3,
                                           int lane, float* mx, float* mn) {
    float s0 = 0.f, s1 = 0.f, s2 = 0.f, s3 = 0.f;
    float x0 = 0.f, x1 = 0.f, x2 = 0.f, x3 = 0.f;
#pragma unroll
    for (int i = 0; i < 5; ++i) {
        float m0 = v0, m1 = v1, m2 = v2, m3 = v3;
#pragma unroll
        for (int off = 32; off; off >>= 1) {
            m0 = fmaxf(m0, __shfl_xor(m0, off, 64));
            m1 = fmaxf(m1, __shfl_xor(m1, off, 64));
            m2 = fmaxf(m2, __shfl_xor(m2, off, 64));
            m3 = fmaxf(m3, __shfl_xor(m3, off, 64));
        }
        if (i == 0) { x0 = m0; x1 = m1; x2 = m2; x3 = m3; }
        s0 += m0; s1 += m1; s2 += m2; s3 += m3;
        unsigned long long k0 = __ballot(v0 == m0);
        unsigned long long k1 = __ballot(v1 == m1);
        unsigned long long k2 = __ballot(v2 == m2);
        unsigned long long k3 = __ballot(v3 == m3);
        if (lane == __ffsll(k0) - 1) v0 = -3.4e38f;
        if (lane == __ffsll(k1) - 1) v1 = -3.4e38f;
        if (lane == __ffsll(k2) - 1) v2 = -3.4e38f;
        if (lane == __ffsll(k3) - 1) v3 = -3.4e38f;
    }
    mx[0] = x0; mx[1] = x1; mx[2] = x2; mx[3] = x3;
    mn[0] = s0 * 0.2f; mn[1] = s1 * 0.2f; mn[2] = s2 * 0.2f; mn[3] = s3 * 0.2f;
}

// ---------- pack conv_w into MFMA B-fragment order; zero qcssq + ctr
__global__ void wb2_kernel(const float* __restrict__ conv_w, short8* __restrict__ Wb2,
                           unsigned int* __restrict__ done_ctr,
                           float* __restrict__ qcssq) {
    if (blockIdx.x == 0 && threadIdx.x == 0) done_ctr[0] = 0u;
    int i = blockIdx.x * 256 + threadIdx.x;
    if (i < NB * NQ) qcssq[i] = 0.f;
    if (i >= 120 * 256) return;
    int rl = i & 15;
    int ftile = (i >> 4) & 15;
    int c = i >> 8;
    int kg = c & 3, rest = c >> 2;
    int ks = rest % 10, j = rest / 10;
    int f = ftile * 16 + rl;
    int k0 = ks * 32 + kg * 8;
    const float* src = conv_w + (size_t)(f * 3 + j) * NE;
    short8 h;
#pragma unroll
    for (int e = 0; e < 8; ++e) {
        int k = k0 + e;
        h[e] = (short)((k < NE) ? f2bf(src[k]) : (unsigned short)0);
    }
    Wb2[i] = h;
}

// ---------- q_emb gather -> taps layout + A-fragments + fp32 q_norm
__global__ void qe_kernel(const int* __restrict__ question, const float* __restrict__ embeds,
                          unsigned short* __restrict__ qe, short8* __restrict__ qef,
                          float* __restrict__ q_norm) {
    int row = blockIdx.x;                        // b*36 + r
    int b = row / QROWS, r = row % QROWS;
    int l = threadIdx.x;
    unsigned short* dst = qe + (size_t)row * KP;
    if (r < NQ) {
        int tok = question[b * NQ + r];
        const float4* rp = (const float4*)(embeds + (size_t)tok * NE);
        short8 h = {0, 0, 0, 0, 0, 0, 0, 0};
        float ss = 0.f;
        if (l < 38) {
            float4 v0 = rp[2 * l];
            ss += v0.x * v0.x + v0.y * v0.y + v0.z * v0.z + v0.w * v0.w;
            h[0] = (short)f2bf(v0.x); h[1] = (short)f2bf(v0.y);
            h[2] = (short)f2bf(v0.z); h[3] = (short)f2bf(v0.w);
            if (2 * l + 1 < 75) {
                float4 v1 = rp[2 * l + 1];
                ss += v1.x * v1.x + v1.y * v1.y + v1.z * v1.z + v1.w * v1.w;
                h[4] = (short)f2bf(v1.x); h[5] = (short)f2bf(v1.y);
                h[6] = (short)f2bf(v1.z); h[7] = (short)f2bf(v1.w);
            }
        }
        if (l < 40) {
            *(short8*)(dst + 8 * l) = h;
            qef[((size_t)(b * 2 + (r >> 4)) * 40 + l) * 16 + (r & 15)] = h;
        }
        ss = wave_reduce_sum(ss);
        if (l == 0) q_norm[b * NQ + r] = sqrtf(ss);
    } else {
        if (l < 40) {
            short8 z = {0, 0, 0, 0, 0, 0, 0, 0};
            *(short8*)(dst + 8 * l) = z;
        }
    }
}

// ---------- q_conv via MFMA -> A-fragments + partial qc ssq
__global__ __launch_bounds__(256) void qconv_mfma_kernel(
        const unsigned short* __restrict__ qe, const short8* __restrict__ Wb2,
        short8* __restrict__ qcf, float* __restrict__ qcssq) {
    __shared__ unsigned short tile[NQ][72];
    int b = blockIdx.x >> 2, fq = blockIdx.x & 3;
    int tid = threadIdx.x, lane = tid & 63, w = tid >> 6;
    int rl = lane & 15, kg = lane >> 4;
    int ftile = fq * 4 + w;
    f32x4 acc0 = (f32x4){0.f, 0.f, 0.f, 0.f};
    f32x4 acc1 = (f32x4){0.f, 0.f, 0.f, 0.f};
    for (int j = 0; j < 3; ++j) {
#pragma unroll 2
        for (int ks = 0; ks < 10; ++ks) {
            int k = ks * 32 + kg * 8;
            int c = (j * 10 + ks) * 4 + kg;
            short8 a0 = *(const short8*)(qe + ((size_t)(b * QROWS) + rl + j) * KP + k);
            short8 a1 = *(const short8*)(qe + ((size_t)(b * QROWS) + 16 + rl + j) * KP + k);
            short8 bb = Wb2[(c * 16 + ftile) * 16 + rl];
            acc0 = MFMA(a0, bb, acc0);
            acc1 = MFMA(a1, bb, acc1);
        }
    }
    int fl = w * 16 + rl;
#pragma unroll
    for (int reg = 0; reg < 4; ++reg) {
        tile[kg * 4 + reg][fl] = f2bf(acc0[reg]);
        tile[16 + kg * 4 + reg][fl] = f2bf(acc1[reg]);
    }
    __syncthreads();
    {
        int mh = tid >> 7, c_local = (tid >> 4) & 7, rl2 = tid & 15;
        short8 h = *(const short8*)(&tile[mh * 16 + rl2][c_local * 8]);
        qcf[((size_t)(b * 2 + mh) * 32 + 8 * fq + c_local) * 16 + rl2] = h;
    }
    {
        int qq = tid >> 3, fgrp = tid & 7;
        short8 h = *(const short8*)(&tile[qq][fgrp * 8]);
        float ss = 0.f;
#pragma unroll
        for (int e = 0; e < 8; ++e) {
            float v = __uint_as_float(((unsigned)(unsigned short)h[e]) << 16);
            ss += v * v;
        }
        ss += __shfl_xor(ss, 1, 64);
        ss += __shfl_xor(ss, 2, 64);
        ss += __shfl_xor(ss, 4, 64);
        if (fgrp == 0) atomicAdd(&qcssq[b * NQ + qq], ss);
    }
}

// ---------- K_pack: s_emb gather -> sB fragments + fp32 snorm; zero scssq
__global__ __launch_bounds__(256) void pack_kernel(
        const int* __restrict__ sentences, const float* __restrict__ embeds,
        short8* __restrict__ sB, float* __restrict__ snorm_g,
        float* __restrict__ scssq) {
    __shared__ unsigned short stg[16][328];
    __shared__ int toks[NL];
    int bs = blockIdx.x;
    int tid = threadIdx.x, lane = tid & 63, w = tid >> 6;
    if (tid < NL) {
        toks[tid] = sentences[(size_t)bs * NL + tid];
        scssq[bs * NL + tid] = 0.f;
    }
    __syncthreads();
    short8* sbb = sB + (size_t)bs * 40 * 64;
    for (int it = 0; it < 4; ++it) {
#pragma unroll
        for (int i = 0; i < 4; ++i) {
            int r16 = w * 4 + i;
            int r = it * 16 + r16;
            const float4* rp = (const float4*)(embeds + (size_t)toks[r] * NE);
            float ss;
            {
                float4 v = rp[lane];
                ss = v.x * v.x + v.y * v.y + v.z * v.z + v.w * v.w;
                ushort4 h = {f2bf(v.x), f2bf(v.y), f2bf(v.z), f2bf(v.w)};
                *(ushort4*)&stg[r16][4 * lane] = h;
            }
            if (lane < 11) {
                float4 v = rp[64 + lane];
                ss += v.x * v.x + v.y * v.y + v.z * v.z + v.w * v.w;
                ushort4 h = {f2bf(v.x), f2bf(v.y), f2bf(v.z), f2bf(v.w)};
                *(ushort4*)&stg[r16][256 + 4 * lane] = h;
            } else if (lane < 16) {
                ushort4 z = {0, 0, 0, 0};
                *(ushort4*)&stg[r16][256 + 4 * lane] = z;
            }
            ss = wave_reduce_sum(ss);
            if (lane == 0) snorm_g[bs * NL + r] = sqrtf(ss);
        }
        __syncthreads();
        {
            int c = tid >> 4, rl = tid & 15;
            for (; c < 40; c += 16) {
                short8 h = *(const short8*)&stg[rl][c * 8];
                sbb[(size_t)c * 64 + it * 16 + rl] = h;
            }
        }
        __syncthreads();
    }
}

// ---------- K_ins: sim_ins MFMA + pool -> fpool_ins (8.6 KB LDS)
__global__ __launch_bounds__(256) void ins_kernel(
        const int* __restrict__ sentences, const int* __restrict__ question,
        const short8* __restrict__ sB, const short8* __restrict__ qef,
        const float* __restrict__ snorm_g, const float* __restrict__ q_norm,
        float2* __restrict__ fpool_ins) {
    __shared__ float sim[NQ][66];
    __shared__ float qn_s[NQ], qmf_s[NQ];
    int bs = blockIdx.x, b = bs / NS;
    int tid = threadIdx.x, lane = tid & 63, w = tid >> 6;
    int rl = lane & 15, kg = lane >> 4;
    int t = (w << 4) + rl;
    if (tid < NQ) qn_s[tid] = q_norm[b * NQ + tid];
    else if (tid < 2 * NQ) {
        int q = tid - NQ;
        qmf_s[q] = (question[b * NQ + q] > 1) ? 1.f : 0.f;
    }
    float sn_t = snorm_g[bs * NL + t];
    float sm_t = (sentences[(size_t)bs * NL + t] > 1) ? 1.f : 0.f;
    __syncthreads();
    f32x4 i0 = (f32x4){0.f, 0.f, 0.f, 0.f};
    f32x4 i1 = (f32x4){0.f, 0.f, 0.f, 0.f};
    const short8* qf = qef + (size_t)(b * 80) * 16;
    const short8* sbb = sB + (size_t)bs * 40 * 64;
#pragma unroll 2
    for (int ks = 0; ks < 10; ++ks) {
        int c = ks * 4 + kg;
        short8 bB = sbb[(size_t)c * 64 + t];
        i0 = MFMA(qf[c * 16 + rl], bB, i0);
        i1 = MFMA(qf[(40 + c) * 16 + rl], bB, i1);
    }
    float inv_t = sm_t / sn_t;
#pragma unroll
    for (int reg = 0; reg < 4; ++reg) {
        int q0 = kg * 4 + reg;
        sim[q0][t] = i0[reg] / qn_s[q0] * inv_t * qmf_s[q0];
        int q1 = 16 + kg * 4 + reg;
        sim[q1][t] = i1[reg] / qn_s[q1] * inv_t * qmf_s[q1];
    }
    __syncthreads();
    int q0 = w << 3;
    float mx[4], mn[4];
    top5_pool4(sim[q0 + 0][lane], sim[q0 + 1][lane], sim[q0 + 2][lane], sim[q0 + 3][lane],
               lane, mx, mn);
    if (lane == 0)
#pragma unroll
        for (int p = 0; p < 4; ++p)
            fpool_ins[(size_t)bs * NQ + q0 + p] = (float2){mx[p], mn[p]};
    top5_pool4(sim[q0 + 4][lane], sim[q0 + 5][lane], sim[q0 + 6][lane], sim[q0 + 7][lane],
               lane, mx, mn);
    if (lane == 0)
#pragma unroll
        for (int p = 0; p < 4; ++p)
            fpool_ins[(size_t)bs * NQ + q0 + 4 + p] = (float2){mx[p], mn[p]};
}

// ---------- K_conv: conv MFMA (A,B from global), transpose via wave-private scratch,
//            emit scB fragments + scssq atomics. LDS = 8.7 KB, no barriers after header.
__global__ __launch_bounds__(256) void conv_kernel(
        const short8* __restrict__ sB, const short8* __restrict__ Wb2,
        short8* __restrict__ scB, float* __restrict__ scssq) {
    __shared__ unsigned short scr[4][16][68];   // wave-private scratch, 8704 B
    int bs = blockIdx.x;
    int tid = threadIdx.x, lane = tid & 63, w = tid >> 6;
    int rl = lane & 15, kg = lane >> 4;
    const short8* sbb = sB + (size_t)bs * 40 * 64;

    f32x4 cacc[4][4];
#pragma unroll
    for (int m = 0; m < 4; ++m)
#pragma unroll
        for (int nn = 0; nn < 4; ++nn) cacc[m][nn] = (f32x4){0.f, 0.f, 0.f, 0.f};

    for (int j = 0; j < 3; ++j) {
#pragma unroll 2
        for (int ks = 0; ks < 10; ++ks) {
            int cA = ks * 4 + kg;
            int c = (j * 10 + ks) * 4 + kg;
            short8 a[4], bb[4];
#pragma unroll
            for (int m = 0; m < 3; ++m)
                a[m] = sbb[(size_t)cA * 64 + m * 16 + rl + j];
            {
                int row3 = 48 + rl + j;
                short8 z = {0, 0, 0, 0, 0, 0, 0, 0};
                a[3] = (row3 < 64) ? sbb[(size_t)cA * 64 + row3] : z;
            }
#pragma unroll
            for (int nn = 0; nn < 4; ++nn)
                bb[nn] = Wb2[(c * 16 + (w * 4 + nn)) * 16 + rl];
#pragma unroll
            for (int m = 0; m < 4; ++m)
#pragma unroll
                for (int nn = 0; nn < 4; ++nn)
                    cacc[m][nn] = MFMA(a[m], bb[nn], cacc[m][nn]);
        }
    }

    // per t-group m: transpose via wave-private scratch (no block barriers)
    short8* scb = scB + (size_t)bs * 32 * 64;
#pragma unroll
    for (int m = 0; m < 4; ++m) {
        // write [16 t][64 f] bf16 patch
#pragma unroll
        for (int nn = 0; nn < 4; ++nn)
#pragma unroll
            for (int reg = 0; reg < 4; ++reg)
                scr[w][kg * 4 + reg][nn * 16 + rl] = f2bf(cacc[m][nn][reg]);
        // norms: ssq over this wave's 64 f for each of 16 t
#pragma unroll
        for (int reg = 0; reg < 4; ++reg) {
            float ss = 0.f;
#pragma unroll
            for (int nn = 0; nn < 4; ++nn) {
                float v = cacc[m][nn][reg];
                ss += v * v;
            }
            ss += __shfl_xor(ss, 1, 64);
            ss += __shfl_xor(ss, 2, 64);
            ss += __shfl_xor(ss, 4, 64);
            ss += __shfl_xor(ss, 8, 64);
            if (rl == 0) atomicAdd(&scssq[bs * NL + m * 16 + kg * 4 + reg], ss);
        }
        // read fragments + global write (2 passes over 8 c-locals)
#pragma unroll
        for (int p = 0; p < 2; ++p) {
            int cl = (lane >> 4) + p * 4;        // 0..7 (f-granule within wave)
            int rl2 = lane & 15;                 // t-local
            short8 v = *(const short8*)&scr[w][rl2][cl * 8];
            scb[(size_t)(w * 8 + cl) * 64 + m * 16 + rl2] = v;
        }
    }
}

// ---------- K_sens: sens MFMA (B from scB fragments) + pools + head + loss
__global__ __launch_bounds__(256) void sens_kernel(
        const float* __restrict__ sim_oh,
        const short8* __restrict__ scB, const short8* __restrict__ qcf,
        const float* __restrict__ qcssq, const float* __restrict__ scssq,
        const float2* __restrict__ fpool_ins,
        const float* __restrict__ lin_w, const float* __restrict__ lin_b,
        const int* __restrict__ tsent, const int* __restrict__ tdoc,
        unsigned int* __restrict__ done_ctr,
        float* __restrict__ sent_ws, float* __restrict__ d_out) {
    __shared__ float sim[NQ][66];
    __shared__ float qcn_s[NQ];
    __shared__ float wq[4];
    __shared__ int lastflag;
    __shared__ float red2[4];
    __shared__ float dred[NB];
    int bs = blockIdx.x, b = bs / NS;
    int tid = threadIdx.x, lane = tid & 63, w = tid >> 6;
    int rl = lane & 15, kg = lane >> 4;
    int t = (w << 4) + rl;
    if (tid < NQ) qcn_s[tid] = sqrtf(qcssq[b * NQ + tid]);
    float scn_t = sqrtf(scssq[bs * NL + t]);
    float oh[8];
#pragma unroll
    for (int qi = 0; qi < 8; ++qi) {
        int q = (w << 3) + qi;
        oh[qi] = sim_oh[((size_t)bs * NQ + q) * NL + lane];
    }
    f32x4 sacc0 = (f32x4){0.f, 0.f, 0.f, 0.f};
    f32x4 sacc1 = (f32x4){0.f, 0.f, 0.f, 0.f};
    const short8* qc = qcf + (size_t)(b * 64) * 16;
    const short8* scb = scB + (size_t)bs * 32 * 64;
#pragma unroll 2
    for (int ks = 0; ks < 8; ++ks) {
        int c = ks * 4 + kg;
        short8 bB = scb[(size_t)c * 64 + t];
        sacc0 = MFMA(qc[c * 16 + rl], bB, sacc0);
        sacc1 = MFMA(qc[(32 + c) * 16 + rl], bB, sacc1);
    }
    __syncthreads();            // qcn_s ready
    float inv_t = 1.f / scn_t;
#pragma unroll
    for (int reg = 0; reg < 4; ++reg) {
        int q0 = kg * 4 + reg;
        sim[q0][t] = sacc0[reg] / qcn_s[q0] * inv_t;
        int q1 = 16 + kg * 4 + reg;
        sim[q1][t] = sacc1[reg] / qcn_s[q1] * inv_t;
    }
    __syncthreads();

    {
        float lw0 = lin_w[0], lw1 = lin_w[1], lw2 = lin_w[2];
        float lw3 = lin_w[3], lw4 = lin_w[4], lw5 = lin_w[5];
        float lb = lin_b[0];
        int q0 = w << 3;
        float mxs[8], mns[8], mxo[8], mno[8];
        top5_pool4(sim[q0 + 0][lane], sim[q0 + 1][lane], sim[q0 + 2][lane],
                   sim[q0 + 3][lane], lane, mxs, mns);
        top5_pool4(sim[q0 + 4][lane], sim[q0 + 5][lane], sim[q0 + 6][lane],
                   sim[q0 + 7][lane], lane, mxs + 4, mns + 4);
        top5_pool4(oh[0], oh[1], oh[2], oh[3], lane, mxo, mno);
        top5_pool4(oh[4], oh[5], oh[6], oh[7], lane, mxo + 4, mno + 4);
        float psum = 0.f;
#pragma unroll
        for (int qi = 0; qi < 8; ++qi) {
            float2 fp = fpool_ins[(size_t)bs * NQ + q0 + qi];
            float z = fp.x * lw0 + fp.y * lw1 + mxs[qi] * lw2 + mns[qi] * lw3 +
                      mxo[qi] * lw4 + mno[qi] * lw5 + lb;
            psum += 1.f / (1.f + expf(-z));
        }
        if (lane == 0) wq[w] = psum;
    }
    __syncthreads();
    if (tid == 0) {
        float sent = (wq[0] + wq[1] + wq[2] + wq[3]) * (1.f / 32.f);
        __hip_atomic_store(&sent_ws[bs], sent, __ATOMIC_RELEASE, __HIP_MEMORY_SCOPE_AGENT);
        d_out[1 + bs] = sent;
        unsigned old = atomicAdd(done_ctr, 1u);
        lastflag = (old == (unsigned)(NB * NS - 1)) ? 1 : 0;
    }
    __syncthreads();

    if (lastflag) {
        float acc_l = 0.f;
        for (int i = tid; i < NB * NS; i += 256) {
            float p = __hip_atomic_load(&sent_ws[i], __ATOMIC_ACQUIRE, __HIP_MEMORY_SCOPE_AGENT);
            float tt2 = (float)tsent[i];
            acc_l += tt2 * logf(p) + (1.f - tt2) * logf(1.f - p);
        }
        acc_l = wave_reduce_sum(acc_l);
        if ((tid & 63) == 0) red2[tid >> 6] = acc_l;
        if (tid < NB) {
            float m = -3.4e38f;
            for (int s = 0; s < NS; ++s)
                m = fmaxf(m, __hip_atomic_load(&sent_ws[tid * NS + s], __ATOMIC_ACQUIRE,
                                               __HIP_MEMORY_SCOPE_AGENT));
            d_out[1 + NB * NS + tid] = m;
            float tt2 = (float)tdoc[tid];
            dred[tid] = tt2 * logf(m) + (1.f - tt2) * logf(1.f - m);
        }
        __syncthreads();
        if (tid == 0) {
            float sal = -(red2[0] + red2[1] + red2[2] + red2[3]) / (float)(NB * NS);
            float dsum = 0.f;
            for (int i = 0; i < NB; ++i) dsum += dred[i];
            float dal = -dsum / (float)NB;
            d_out[0] = 0.5f * (sal + dal);
        }
    }
}

extern "C" void kernel_launch(void* const* d_in, const int* in_sizes, int n_in,
                              void* d_out, int out_size, void* d_ws, size_t ws_size,
                              hipStream_t stream) {
    const int* sentences = (const int*)d_in[0];
    const int* question = (const int*)d_in[1];
    const int* tsent = (const int*)d_in[2];
    const int* tdoc = (const int*)d_in[3];
    const float* sim_oh = (const float*)d_in[4];
    const float* embeds = (const float*)d_in[5];
    const float* conv_w = (const float*)d_in[6];
    const float* lin_w = (const float*)d_in[7];
    const float* lin_b = (const float*)d_in[8];
    float* out = (float*)d_out;

    char* wsc = (char*)d_ws;
    short8* Wb2            = (short8*)(wsc);                     // 491520 B
    unsigned short* qe_old = (unsigned short*)(wsc + 491520);    // 368640 B
    short8* qef            = (short8*)(wsc + 860160);            // 327680 B
    short8* qcf            = (short8*)(wsc + 1187840);           // 262144 B
    float* q_norm          = (float*)(wsc + 1449984);            // 2048 B
    float* qcssq           = (float*)(wsc + 1452032);            // 2048 B
    float* sent_ws         = (float*)(wsc + 1454080);            // 3072 B
    unsigned int* done_ctr = (unsigned int*)(wsc + 1457152);     // 16 B
    float* snorm_g         = (float*)(wsc + 1457168);            // 196608 B
    float* scssq           = (float*)(wsc + 1653776);            // 196608 B
    float2* fpool_ins      = (float2*)(wsc + 1850384);           // 196608 B
    short8* sB             = (short8*)(wsc + 2046992);           // 31457280 B
    short8* scB            = (short8*)(wsc + 33504272);          // 25165824 B

    wb2_kernel<<<120, 256, 0, stream>>>(conv_w, Wb2, done_ctr, qcssq);
    qe_kernel<<<NB * QROWS, 64, 0, stream>>>(question, embeds, qe_old, qef, q_norm);
    qconv_mfma_kernel<<<NB * 4, 256, 0, stream>>>(qe_old, Wb2, qcf, qcssq);
    pack_kernel<<<NB * NS, 256, 0, stream>>>(sentences, embeds, sB, snorm_g, scssq);
    ins_kernel<<<NB * NS, 256, 0, stream>>>(sentences, question, sB, qef,
                                            snorm_g, q_norm, fpool_ins);
    conv_kernel<<<NB * NS, 256, 0, stream>>>(sB, Wb2, scB, scssq);
    sens_kernel<<<NB * NS, 256, 0, stream>>>(
        sim_oh, scB, qcf, qcssq, scssq, fpool_ins,
        lin_w, lin_b, tsent, tdoc, done_ctr, sent_ws, out);
}